// Round 13
// baseline (182.951 us; speedup 1.0000x reference)
//
#include <hip/hip_runtime.h>

// Problem constants: N=50000, E=600000, D=128, G=8. All float tensors are f32.
// NOTE: edge packing requires N < 65536 (src in 16 bits) — holds here.
#define D 128
#define NGRAPH 8
#define EPS 1e-5f
#define BINCAP 160   // entries per 8-node bin; mean 96, sd ~10 -> overflow P ~ 1e-10

typedef __attribute__((ext_vector_type(4))) float f32x4;
typedef __attribute__((ext_vector_type(2))) float f32x2;
typedef __attribute__((ext_vector_type(8))) short s16x8;

__device__ __forceinline__ unsigned short f2bf(float f) {
    unsigned int u = __float_as_uint(f);
    u += 0x7fffu + ((u >> 16) & 1u);     // round-to-nearest-even
    return (unsigned short)(u >> 16);
}
__device__ __forceinline__ float blo(unsigned int u) { return __uint_as_float(u << 16); }
__device__ __forceinline__ float bhi(unsigned int u) { return __uint_as_float(u & 0xffff0000u); }

// ---- prep_fill (block-ranged): [0,128) Bsw | [128] bounds | edge binning | xb+xf8 cast ----
__global__ __launch_bounds__(256) void prep_fill_kernel(
    const float* __restrict__ Wl, const float* __restrict__ Wr,
    unsigned short* __restrict__ Bsw,
    const float* __restrict__ x, unsigned int* __restrict__ xb,
    unsigned int* __restrict__ xf8,
    const int* __restrict__ batch, int* __restrict__ bnd,
    const int* __restrict__ ei, unsigned int* __restrict__ bcnt,
    unsigned int* __restrict__ bbuf,
    int N, int E, int Npad, int fillB)
{
    int b = blockIdx.x;
    if (b < 128) {                      // B = [Wl;Wr]^T in MFMA-fragment order
        int t = b * 256 + threadIdx.x;             // 0..32767
        int j    = t & 7;
        int ln   = (t >> 3) & 63;
        int ks   = (t >> 9) & 7;
        int tile = t >> 12;
        int k = ks * 32 + (ln >> 4) * 8 + j;
        int d = tile * 16 + (ln & 15);
        float v = (k < 128) ? Wl[(size_t)d * 128 + k] : Wr[(size_t)d * 128 + (k - 128)];
        Bsw[t] = f2bf(v);
    } else if (b == 128) {              // graph boundaries (batch sorted)
        int g = threadIdx.x;
        if (g <= NGRAPH) {
            int lo = 0, hi = N;
            while (lo < hi) {
                int mid = (lo + hi) >> 1;
                if (batch[mid] < g) lo = mid + 1; else hi = mid;
            }
            bnd[g] = lo;
        }
    } else if (b < 129 + fillB) {       // edge binning: bin = dst>>3 (8-node bins)
        int e = (b - 129) * 256 + threadIdx.x;
        if (e < E) {
            int dst = ei[E + e];
            int src = ei[e];
            int bin = dst >> 3;
            unsigned int pos = atomicAdd(&bcnt[(size_t)bin * 16], 1u);  // 1 counter / 64B line
            if (pos < BINCAP)
                bbuf[(size_t)bin * BINCAP + pos] =
                    (unsigned int)src | ((unsigned int)(dst & 7) << 16);
        }
    } else {                            // x -> bf16 pairs + fp8 row, zero-padded
        int iu = (b - 129 - fillB) * 256 + threadIdx.x;   // covers 4 features
        if (iu < Npad * 32) {
            int n = iu >> 5, slot = iu & 31;
            if (iu < N * 32) {
                float4 p = *(const float4*)(x + (size_t)iu * 4);
                uint2 o;
                o.x = (unsigned int)f2bf(p.x) | ((unsigned int)f2bf(p.y) << 16);
                o.y = (unsigned int)f2bf(p.z) | ((unsigned int)f2bf(p.w) << 16);
                *(uint2*)(xb + (size_t)iu * 2) = o;
                int u8 = __builtin_amdgcn_cvt_pk_fp8_f32(p.x, p.y, 0, false);
                u8     = __builtin_amdgcn_cvt_pk_fp8_f32(p.z, p.w, u8, true);
                xf8[(size_t)n * 32 + slot] = (unsigned int)u8;
            } else {
                *(uint2*)(xb + (size_t)iu * 2) = make_uint2(0u, 0u);
                xf8[(size_t)n * 32 + slot] = 0u;
            }
        }
    }
}

// ---- Fused aggregate+gemm: block = 16 nodes = 2 edge bins; 3128 blocks -> full
//      8-block/CU residency (r12 was 1564 blocks = 47% occupancy, grid-limited).
//      Phase A0: LDS counting-sort of both bins' entries by local dst (0..15).
//      Phase A: wave gathers 4 nodes (register accumulate, 8-wide unrolled fp8 rows).
//      Phase B: all 4 waves share the 16 MFMA rows; wave computes 2 tiles.
__global__ __launch_bounds__(256, 8) void fused_kernel(
    const unsigned short* __restrict__ xf8,
    const unsigned int* __restrict__ bcnt, const unsigned int* __restrict__ bbuf,
    const unsigned short* __restrict__ xb16, const unsigned short* __restrict__ Bsw,
    const float* __restrict__ bl, const int* __restrict__ batch,
    float* __restrict__ gsum, float* __restrict__ gsumsq,
    unsigned short* __restrict__ fout16, int N)
{
    __shared__ unsigned int aggL[16][68];        // 4.35 KB; +4 pad
    __shared__ unsigned short sortedL[2 * BINCAP];  // 640 B
    __shared__ int histL[16];
    __shared__ int startL[16];
    __shared__ int offsL[16];

    int wave = threadIdx.x >> 6, lane = threadIdx.x & 63;
    int nblk0 = blockIdx.x * 16;
    int bin0 = blockIdx.x * 2;

    if (threadIdx.x < 16) histL[threadIdx.x] = 0;
    __syncthreads();

    // ---- phase A0: load both bins + histogram + prefix + scatter (counting sort) ----
    int ec0 = (int)bcnt[(size_t)bin0 * 16];       if (ec0 > BINCAP) ec0 = BINCAP;
    int ec1 = (int)bcnt[(size_t)(bin0 + 1) * 16]; if (ec1 > BINCAP) ec1 = BINCAP;
    int ec = ec0 + ec1;
    const unsigned int* bb0 = bbuf + (size_t)bin0 * BINCAP;
    const unsigned int* bb1 = bbuf + (size_t)(bin0 + 1) * BINCAP;
    int t0 = threadIdx.x, t1 = threadIdx.x + 256;
    unsigned int ent0 = 0u, ent1 = 0u;
    int dl0 = 0, dl1 = 0;
    if (t0 < ec) {
        ent0 = (t0 < ec0) ? bb0[t0] : bb1[t0 - ec0];
        dl0  = (int)(ent0 >> 16) + ((t0 < ec0) ? 0 : 8);
        atomicAdd(&histL[dl0], 1);
    }
    if (t1 < ec) {
        ent1 = (t1 < ec0) ? bb0[t1] : bb1[t1 - ec0];
        dl1  = (int)(ent1 >> 16) + ((t1 < ec0) ? 0 : 8);
        atomicAdd(&histL[dl1], 1);
    }
    __syncthreads();
    if (threadIdx.x == 0) {
        int acc = 0;
        for (int i = 0; i < 16; ++i) { startL[i] = acc; offsL[i] = acc; acc += histL[i]; }
    }
    __syncthreads();
    if (t0 < ec) { int p = atomicAdd(&offsL[dl0], 1); sortedL[p] = (unsigned short)(ent0 & 0xffffu); }
    if (t1 < ec) { int p = atomicAdd(&offsL[dl1], 1); sortedL[p] = (unsigned short)(ent1 & 0xffffu); }
    __syncthreads();

    // ---- phase A: wave-cooperative fp8 gather, 4 nodes per wave ----
#pragma unroll
    for (int s = 0; s < 4; ++s) {
        int ln = wave * 4 + s;          // local node 0..15 (wave-uniform)
        int dgn = histL[ln];
        int base = startL[ln];
        float a0 = 0.0f, a1 = 0.0f;
        int i = 0;
        for (; i + 8 <= dgn; i += 8) {
            int nb[8];
#pragma unroll
            for (int k = 0; k < 8; ++k) nb[k] = sortedL[base + i + k];   // LDS broadcast
            unsigned short u[8];
#pragma unroll
            for (int k = 0; k < 8; ++k) u[k] = xf8[(size_t)nb[k] * 64 + lane];
#pragma unroll
            for (int k = 0; k < 8; ++k) {
                f32x2 d2 = __builtin_amdgcn_cvt_pk_f32_fp8((int)(unsigned int)u[k], false);
                a0 += d2[0]; a1 += d2[1];
            }
        }
        for (; i < dgn; ++i) {
            int nb = sortedL[base + i];
            f32x2 d2 = __builtin_amdgcn_cvt_pk_f32_fp8(
                (int)(unsigned int)xf8[(size_t)nb * 64 + lane], false);
            a0 += d2[0]; a1 += d2[1];
        }
        float iv = 1.0f / (float)(dgn > 0 ? dgn : 1);
        aggL[ln][lane] =
            (unsigned int)f2bf(a0 * iv) | ((unsigned int)f2bf(a1 * iv) << 16);
    }
    __syncthreads();

    // ---- phase B: all waves share 16 rows; wave computes tiles wave*2, wave*2+1 ----
    int m = lane & 15, quad = lane >> 4;
    int r = nblk0 + m;

    s16x8 afrag[8];
#pragma unroll
    for (int ks = 0; ks < 4; ++ks)
        afrag[ks] = *(const s16x8*)&aggL[m][ks * 16 + quad * 4];
    const unsigned short* xp = xb16 + (size_t)r * 128 + quad * 8;
#pragma unroll
    for (int ks = 0; ks < 4; ++ks) afrag[4 + ks] = *(const s16x8*)(xp + ks * 32);

    int nbase = nblk0;
    bool uni = (nbase + 15 < N) && (batch[nbase] == batch[nbase + 15]);
    int gu = (nbase < N) ? batch[nbase] : 0;

#pragma unroll
    for (int t = 0; t < 2; ++t) {
        int tile = wave * 2 + t;
        f32x4 acc = {0.0f, 0.0f, 0.0f, 0.0f};
        const s16x8* bptr = (const s16x8*)Bsw + (size_t)(tile * 8) * 64 + lane;
#pragma unroll
        for (int ks = 0; ks < 8; ++ks)
            acc = __builtin_amdgcn_mfma_f32_16x16x32_bf16(afrag[ks], bptr[(size_t)ks * 64], acc, 0, 0, 0);
        int d = tile * 16 + m;
        float bias = bl[d];
        float sm = 0.0f, sq = 0.0f;
#pragma unroll
        for (int rr = 0; rr < 4; ++rr) {
            int node = nbase + quad * 4 + rr;   // C/D: col=lane&15, row=quad*4+reg
            float v = acc[rr] + bias;
            float g = 0.5f * v * (1.0f + erff(v * 0.70710678118654752f));
            if (node < N) {
                fout16[(size_t)node * 128 + d] = f2bf(g);
                if (uni) { sm += g; sq += g * g; }
                else {
                    int gg = batch[node];
                    unsafeAtomicAdd(&gsum[gg * D + d], g);
                    unsafeAtomicAdd(&gsumsq[gg * D + d], g * g);
                }
            }
        }
        if (uni) {
            sm += __shfl_xor(sm, 16, 64); sm += __shfl_xor(sm, 32, 64);
            sq += __shfl_xor(sq, 16, 64); sq += __shfl_xor(sq, 32, 64);
            if (quad == 0) {
                unsafeAtomicAdd(&gsum[gu * D + d], sm);
                unsafeAtomicAdd(&gsumsq[gu * D + d], sq);
            }
        }
    }
}

// ---- final: dispatch boundary makes stats coherent+cacheable; bf16 f decode.
//      out = (f - ms*mu)*rsqrt(var+eps)*gw + gb + x
__global__ __launch_bounds__(256) void final_kernel(
    const unsigned int* __restrict__ f16, const float* __restrict__ x,
    const int* __restrict__ batch, const int* __restrict__ bnd,
    const float* __restrict__ gsum, const float* __restrict__ gsumsq,
    const float* __restrict__ ms,
    const float* __restrict__ gw, const float* __restrict__ gb,
    float* __restrict__ out, int N)
{
    int t = blockIdx.x * 256 + threadIdx.x;      // one thread per 4 features
    if (t >= N * (D / 4)) return;
    int n  = t >> 5;
    int d0 = (t & 31) * 4;
    int g  = batch[n];
    int c  = bnd[g + 1] - bnd[g];
    float invc = 1.0f / (float)(c > 0 ? c : 1);
    size_t row = (size_t)n * D + d0;
    uint2 fu = *(const uint2*)(f16 + (size_t)n * 64 + (d0 >> 1));
    float4 fv = make_float4(blo(fu.x), bhi(fu.x), blo(fu.y), bhi(fu.y));
    float4 xv = *(const float4*)(x + row);
    float4 s1 = *(const float4*)(gsum + g * D + d0);
    float4 s2 = *(const float4*)(gsumsq + g * D + d0);
    float4 msv = *(const float4*)(ms + d0);
    float4 gwv = *(const float4*)(gw + d0);
    float4 gbv = *(const float4*)(gb + d0);
    float4 o;
    {
        float mu = s1.x * invc, q = s2.x * invc, a = msv.x * mu;
        float sc = rsqrtf(q - 2.0f * a * mu + a * a + EPS);
        o.x = (fv.x - a) * sc * gwv.x + gbv.x + xv.x;
    }
    {
        float mu = s1.y * invc, q = s2.y * invc, a = msv.y * mu;
        float sc = rsqrtf(q - 2.0f * a * mu + a * a + EPS);
        o.y = (fv.y - a) * sc * gwv.y + gbv.y + xv.y;
    }
    {
        float mu = s1.z * invc, q = s2.z * invc, a = msv.z * mu;
        float sc = rsqrtf(q - 2.0f * a * mu + a * a + EPS);
        o.z = (fv.z - a) * sc * gwv.z + gbv.z + xv.z;
    }
    {
        float mu = s1.w * invc, q = s2.w * invc, a = msv.w * mu;
        float sc = rsqrtf(q - 2.0f * a * mu + a * a + EPS);
        o.w = (fv.w - a) * sc * gwv.w + gbv.w + xv.w;
    }
    *(float4*)(out + row) = o;
}

extern "C" void kernel_launch(void* const* d_in, const int* in_sizes, int n_in,
                              void* d_out, int out_size, void* d_ws, size_t ws_size,
                              hipStream_t stream)
{
    const float* x     = (const float*)d_in[0];
    const int*   ei    = (const int*)d_in[1];
    const int*   batch = (const int*)d_in[2];
    const float* Wl = (const float*)d_in[4];
    const float* bl = (const float*)d_in[5];
    const float* Wr = (const float*)d_in[6];
    const float* gw = (const float*)d_in[7];
    const float* gb = (const float*)d_in[8];
    const float* ms = (const float*)d_in[9];
    float* out = (float*)d_out;

    int N = in_sizes[0] / D;
    int E = in_sizes[1] / 2;
    int NBLK = (N + 63) / 64;
    int Npad = NBLK * 64;
    int NBIN = Npad / 8;                         // 6256 edge bins (8 nodes each)
    int NB16 = Npad / 16;                        // 3128 fused blocks (16 nodes each)

    // workspace layout (~37 MB, no aliasing):
    //   fout16 [Npad*64 uint bf16-pairs] | xf8 [Npad*32 uint] | xb [Npad*64 uint]
    //   | Bsw [32768 bf16] | gsum | gsumsq [G*D f32] | pad[4]
    //   | bcnt [NBIN*16 uint, 1 counter/64B line] | bnd[G+1] | bbuf [NBIN*BINCAP uint]
    unsigned int*   fout16 = (unsigned int*)d_ws;
    unsigned int*   xf8  = fout16 + (size_t)Npad * 64;
    unsigned int*   xb   = xf8 + (size_t)Npad * 32;
    unsigned short* Bsw  = (unsigned short*)(xb + (size_t)Npad * 64);
    float* gsum   = (float*)(Bsw + 32768);
    float* gsumsq = gsum + NGRAPH * D;
    unsigned int* pad  = (unsigned int*)(gsumsq + NGRAPH * D);
    unsigned int* bcnt = pad + 4;
    int*          bnd  = (int*)(bcnt + (size_t)NBIN * 16);
    unsigned int* bbuf = (unsigned int*)(bnd + (NGRAPH + 1));

    // zero gsum, gsumsq, pad, bcnt (contiguous ~410 KB)
    hipMemsetAsync(gsum, 0,
                   (2 * NGRAPH * D) * sizeof(float) + 4 * sizeof(unsigned int)
                   + (size_t)NBIN * 16 * sizeof(unsigned int), stream);

    int fillB = (E + 255) / 256;
    int xbB   = (Npad * 32 + 255) / 256;
    prep_fill_kernel<<<129 + fillB + xbB, 256, 0, stream>>>(
        Wl, Wr, Bsw, x, xb, xf8, batch, bnd, ei, bcnt, bbuf, N, E, Npad, fillB);

    // fused bin-sort gather + gemm (block = 16 nodes = 2 bins, 8 blk/CU)
    fused_kernel<<<NB16, 256, 0, stream>>>(
        (const unsigned short*)xf8, bcnt, bbuf,
        (const unsigned short*)xb, Bsw, bl, batch,
        gsum, gsumsq, (unsigned short*)fout16, N);

    {
        int threads = N * (D / 4);
        final_kernel<<<(threads + 255) / 256, 256, 0, stream>>>(
            fout16, x, batch, bnd, gsum, gsumsq, ms, gw, gb, out, N);
    }
}

// Round 14
// 179.481 us; speedup vs baseline: 1.0193x; 1.0193x over previous
//
#include <hip/hip_runtime.h>

// Problem constants: N=50000, E=600000, D=128, G=8. All float tensors are f32.
// NOTE: edge packing requires N < 65536 (src in 16 bits) — holds here.
#define D 128
#define NGRAPH 8
#define EPS 1e-5f
#define BINCAP 512   // entries per 32-node bin; mean 384, sd ~20 -> overflow P ~ 0

typedef __attribute__((ext_vector_type(4))) float f32x4;
typedef __attribute__((ext_vector_type(2))) float f32x2;
typedef __attribute__((ext_vector_type(8))) short s16x8;

__device__ __forceinline__ unsigned short f2bf(float f) {
    unsigned int u = __float_as_uint(f);
    u += 0x7fffu + ((u >> 16) & 1u);     // round-to-nearest-even
    return (unsigned short)(u >> 16);
}
__device__ __forceinline__ float blo(unsigned int u) { return __uint_as_float(u << 16); }
__device__ __forceinline__ float bhi(unsigned int u) { return __uint_as_float(u & 0xffff0000u); }

// ---- prep_fill (block-ranged): [0,128) Bsw | [128] bounds | edge binning x4 | xb+xf8 cast ----
__global__ __launch_bounds__(256) void prep_fill_kernel(
    const float* __restrict__ Wl, const float* __restrict__ Wr,
    unsigned short* __restrict__ Bsw,
    const float* __restrict__ x, unsigned int* __restrict__ xb,
    unsigned int* __restrict__ xf8,
    const int* __restrict__ batch, int* __restrict__ bnd,
    const int* __restrict__ ei, unsigned int* __restrict__ bcnt,
    unsigned int* __restrict__ bbuf,
    int N, int E, int Npad, int fillB)
{
    int b = blockIdx.x;
    if (b < 128) {                      // B = [Wl;Wr]^T in MFMA-fragment order
        int t = b * 256 + threadIdx.x;             // 0..32767
        int j    = t & 7;
        int ln   = (t >> 3) & 63;
        int ks   = (t >> 9) & 7;
        int tile = t >> 12;
        int k = ks * 32 + (ln >> 4) * 8 + j;
        int d = tile * 16 + (ln & 15);
        float v = (k < 128) ? Wl[(size_t)d * 128 + k] : Wr[(size_t)d * 128 + (k - 128)];
        Bsw[t] = f2bf(v);
    } else if (b == 128) {              // graph boundaries (batch sorted)
        int g = threadIdx.x;
        if (g <= NGRAPH) {
            int lo = 0, hi = N;
            while (lo < hi) {
                int mid = (lo + hi) >> 1;
                if (batch[mid] < g) lo = mid + 1; else hi = mid;
            }
            bnd[g] = lo;
        }
    } else if (b < 129 + fillB) {       // edge binning, 4 edges/thread (int4 ei loads)
        int e0 = ((b - 129) * 256 + threadIdx.x) * 4;
        if (e0 + 4 <= E) {
            int4 s4 = *(const int4*)(ei + e0);
            int4 d4 = *(const int4*)(ei + E + e0);
#pragma unroll
            for (int k = 0; k < 4; ++k) {
                int src = (&s4.x)[k], dst = (&d4.x)[k];
                int bin = dst >> 5;
                unsigned int pos = atomicAdd(&bcnt[(size_t)bin * 16], 1u);
                if (pos < BINCAP)
                    bbuf[(size_t)bin * BINCAP + pos] =
                        (unsigned int)src | ((unsigned int)(dst & 31) << 16);
            }
        } else {
            for (int e = e0; e < E; ++e) {
                int dst = ei[E + e];
                int src = ei[e];
                int bin = dst >> 5;
                unsigned int pos = atomicAdd(&bcnt[(size_t)bin * 16], 1u);
                if (pos < BINCAP)
                    bbuf[(size_t)bin * BINCAP + pos] =
                        (unsigned int)src | ((unsigned int)(dst & 31) << 16);
            }
        }
    } else {                            // x -> bf16 pairs + fp8 row, zero-padded
        int iu = (b - 129 - fillB) * 256 + threadIdx.x;   // covers 4 features
        if (iu < Npad * 32) {
            int n = iu >> 5, slot = iu & 31;
            if (iu < N * 32) {
                float4 p = *(const float4*)(x + (size_t)iu * 4);
                uint2 o;
                o.x = (unsigned int)f2bf(p.x) | ((unsigned int)f2bf(p.y) << 16);
                o.y = (unsigned int)f2bf(p.z) | ((unsigned int)f2bf(p.w) << 16);
                *(uint2*)(xb + (size_t)iu * 2) = o;
                int u8 = __builtin_amdgcn_cvt_pk_fp8_f32(p.x, p.y, 0, false);
                u8     = __builtin_amdgcn_cvt_pk_fp8_f32(p.z, p.w, u8, true);
                xf8[(size_t)n * 32 + slot] = (unsigned int)u8;
            } else {
                *(uint2*)(xb + (size_t)iu * 2) = make_uint2(0u, 0u);
                xf8[(size_t)n * 32 + slot] = 0u;
            }
        }
    }
}

// ---- Fused aggregate+gemm (r12 proven config): block = 32 nodes = 1 edge bin.
//      Phase A0: LDS counting-sort of the bin's entries by local dst (384 LDS atomics).
//      Phase A: wave gathers 8 nodes (register accumulate, 8-wide unrolled fp8 rows,
//      neighbor indices via LDS broadcast). Phase B: split-tile MFMA (wave = 16 nodes
//      x 4 tiles) + GELU + stats atomics + bf16 fout.
__global__ __launch_bounds__(256, 8) void fused_kernel(
    const unsigned short* __restrict__ xf8,
    const unsigned int* __restrict__ bcnt, const unsigned int* __restrict__ bbuf,
    const unsigned short* __restrict__ xb16, const unsigned short* __restrict__ Bsw,
    const float* __restrict__ bl, const int* __restrict__ batch,
    float* __restrict__ gsum, float* __restrict__ gsumsq,
    unsigned short* __restrict__ fout16, int N)
{
    __shared__ unsigned int aggL[32][68];       // 8.7 KB; +4 pad -> 2-way conflicts only
    __shared__ unsigned short sortedL[BINCAP];  // 1 KB: src indices sorted by local dst
    __shared__ int histL[32];
    __shared__ int startL[32];
    __shared__ int offsL[32];

    int wave = threadIdx.x >> 6, lane = threadIdx.x & 63;
    int bin = blockIdx.x;
    int nblk0 = bin * 32;

    if (threadIdx.x < 32) histL[threadIdx.x] = 0;
    __syncthreads();

    // ---- phase A0: load entries + histogram + prefix + scatter (counting sort) ----
    int ec = (int)bcnt[(size_t)bin * 16];
    if (ec > BINCAP) ec = BINCAP;
    const unsigned int* bb = bbuf + (size_t)bin * BINCAP;
    int t0 = threadIdx.x, t1 = threadIdx.x + 256;
    unsigned int ent0 = 0u, ent1 = 0u;
    if (t0 < ec) { ent0 = bb[t0]; atomicAdd(&histL[ent0 >> 16], 1); }
    if (t1 < ec) { ent1 = bb[t1]; atomicAdd(&histL[ent1 >> 16], 1); }
    __syncthreads();
    if (threadIdx.x == 0) {
        int acc = 0;
        for (int i = 0; i < 32; ++i) { startL[i] = acc; offsL[i] = acc; acc += histL[i]; }
    }
    __syncthreads();
    if (t0 < ec) { int p = atomicAdd(&offsL[ent0 >> 16], 1); sortedL[p] = (unsigned short)(ent0 & 0xffffu); }
    if (t1 < ec) { int p = atomicAdd(&offsL[ent1 >> 16], 1); sortedL[p] = (unsigned short)(ent1 & 0xffffu); }
    __syncthreads();

    // ---- phase A: wave-cooperative fp8 gather, 8 nodes per wave ----
#pragma unroll
    for (int s = 0; s < 8; ++s) {
        int ln = wave * 8 + s;          // local node 0..31 (wave-uniform)
        int dgn = histL[ln];
        int base = startL[ln];
        float a0 = 0.0f, a1 = 0.0f;
        int i = 0;
        for (; i + 8 <= dgn; i += 8) {
            int nb[8];
#pragma unroll
            for (int k = 0; k < 8; ++k) nb[k] = sortedL[base + i + k];   // LDS broadcast
            unsigned short u[8];
#pragma unroll
            for (int k = 0; k < 8; ++k) u[k] = xf8[(size_t)nb[k] * 64 + lane];
#pragma unroll
            for (int k = 0; k < 8; ++k) {
                f32x2 d2 = __builtin_amdgcn_cvt_pk_f32_fp8((int)(unsigned int)u[k], false);
                a0 += d2[0]; a1 += d2[1];
            }
        }
        for (; i < dgn; ++i) {
            int nb = sortedL[base + i];
            f32x2 d2 = __builtin_amdgcn_cvt_pk_f32_fp8(
                (int)(unsigned int)xf8[(size_t)nb * 64 + lane], false);
            a0 += d2[0]; a1 += d2[1];
        }
        float iv = 1.0f / (float)(dgn > 0 ? dgn : 1);
        aggL[ln][lane] =
            (unsigned int)f2bf(a0 * iv) | ((unsigned int)f2bf(a1 * iv) << 16);
    }
    __syncthreads();

    // ---- phase B: split-tile gemm (wave = 16 nodes x 4 tiles) ----
    int row0 = nblk0 + (wave >> 1) * 16;   // two waves share 16 rows
    int th = wave & 1;                     // tile half: tiles th*4..th*4+3
    int m = lane & 15, quad = lane >> 4;
    int r = row0 + m;
    int lr = (wave >> 1) * 16 + m;         // local LDS row

    s16x8 afrag[8];
#pragma unroll
    for (int ks = 0; ks < 4; ++ks)
        afrag[ks] = *(const s16x8*)&aggL[lr][ks * 16 + quad * 4];
    const unsigned short* xp = xb16 + (size_t)r * 128 + quad * 8;
#pragma unroll
    for (int ks = 0; ks < 4; ++ks) afrag[4 + ks] = *(const s16x8*)(xp + ks * 32);

    int nbase = row0;
    bool uni = (nbase + 15 < N) && (batch[nbase] == batch[nbase + 15]);
    int gu = (nbase < N) ? batch[nbase] : 0;

#pragma unroll
    for (int t = 0; t < 4; ++t) {
        int tile = th * 4 + t;
        f32x4 acc = {0.0f, 0.0f, 0.0f, 0.0f};
        const s16x8* bptr = (const s16x8*)Bsw + (size_t)(tile * 8) * 64 + lane;
#pragma unroll
        for (int ks = 0; ks < 8; ++ks)
            acc = __builtin_amdgcn_mfma_f32_16x16x32_bf16(afrag[ks], bptr[(size_t)ks * 64], acc, 0, 0, 0);
        int d = tile * 16 + m;
        float bias = bl[d];
        float sm = 0.0f, sq = 0.0f;
#pragma unroll
        for (int rr = 0; rr < 4; ++rr) {
            int node = nbase + quad * 4 + rr;   // C/D: col=lane&15, row=quad*4+reg
            float v = acc[rr] + bias;
            float g = 0.5f * v * (1.0f + erff(v * 0.70710678118654752f));
            if (node < N) {
                fout16[(size_t)node * 128 + d] = f2bf(g);
                if (uni) { sm += g; sq += g * g; }
                else {
                    int gg = batch[node];
                    unsafeAtomicAdd(&gsum[gg * D + d], g);
                    unsafeAtomicAdd(&gsumsq[gg * D + d], g * g);
                }
            }
        }
        if (uni) {
            sm += __shfl_xor(sm, 16, 64); sm += __shfl_xor(sm, 32, 64);
            sq += __shfl_xor(sq, 16, 64); sq += __shfl_xor(sq, 32, 64);
            if (quad == 0) {
                unsafeAtomicAdd(&gsum[gu * D + d], sm);
                unsafeAtomicAdd(&gsumsq[gu * D + d], sq);
            }
        }
    }
}

// ---- final: dispatch boundary makes stats coherent+cacheable; bf16 f decode.
//      out = (f - ms*mu)*rsqrt(var+eps)*gw + gb + x
__global__ __launch_bounds__(256) void final_kernel(
    const unsigned int* __restrict__ f16, const float* __restrict__ x,
    const int* __restrict__ batch, const int* __restrict__ bnd,
    const float* __restrict__ gsum, const float* __restrict__ gsumsq,
    const float* __restrict__ ms,
    const float* __restrict__ gw, const float* __restrict__ gb,
    float* __restrict__ out, int N)
{
    int t = blockIdx.x * 256 + threadIdx.x;      // one thread per 4 features
    if (t >= N * (D / 4)) return;
    int n  = t >> 5;
    int d0 = (t & 31) * 4;
    int g  = batch[n];
    int c  = bnd[g + 1] - bnd[g];
    float invc = 1.0f / (float)(c > 0 ? c : 1);
    size_t row = (size_t)n * D + d0;
    uint2 fu = *(const uint2*)(f16 + (size_t)n * 64 + (d0 >> 1));
    float4 fv = make_float4(blo(fu.x), bhi(fu.x), blo(fu.y), bhi(fu.y));
    float4 xv = *(const float4*)(x + row);
    float4 s1 = *(const float4*)(gsum + g * D + d0);
    float4 s2 = *(const float4*)(gsumsq + g * D + d0);
    float4 msv = *(const float4*)(ms + d0);
    float4 gwv = *(const float4*)(gw + d0);
    float4 gbv = *(const float4*)(gb + d0);
    float4 o;
    {
        float mu = s1.x * invc, q = s2.x * invc, a = msv.x * mu;
        float sc = rsqrtf(q - 2.0f * a * mu + a * a + EPS);
        o.x = (fv.x - a) * sc * gwv.x + gbv.x + xv.x;
    }
    {
        float mu = s1.y * invc, q = s2.y * invc, a = msv.y * mu;
        float sc = rsqrtf(q - 2.0f * a * mu + a * a + EPS);
        o.y = (fv.y - a) * sc * gwv.y + gbv.y + xv.y;
    }
    {
        float mu = s1.z * invc, q = s2.z * invc, a = msv.z * mu;
        float sc = rsqrtf(q - 2.0f * a * mu + a * a + EPS);
        o.z = (fv.z - a) * sc * gwv.z + gbv.z + xv.z;
    }
    {
        float mu = s1.w * invc, q = s2.w * invc, a = msv.w * mu;
        float sc = rsqrtf(q - 2.0f * a * mu + a * a + EPS);
        o.w = (fv.w - a) * sc * gwv.w + gbv.w + xv.w;
    }
    *(float4*)(out + row) = o;
}

extern "C" void kernel_launch(void* const* d_in, const int* in_sizes, int n_in,
                              void* d_out, int out_size, void* d_ws, size_t ws_size,
                              hipStream_t stream)
{
    const float* x     = (const float*)d_in[0];
    const int*   ei    = (const int*)d_in[1];
    const int*   batch = (const int*)d_in[2];
    const float* Wl = (const float*)d_in[4];
    const float* bl = (const float*)d_in[5];
    const float* Wr = (const float*)d_in[6];
    const float* gw = (const float*)d_in[7];
    const float* gb = (const float*)d_in[8];
    const float* ms = (const float*)d_in[9];
    float* out = (float*)d_out;

    int N = in_sizes[0] / D;
    int E = in_sizes[1] / 2;
    int NBLK = (N + 63) / 64;
    int Npad = NBLK * 64;
    int NB32 = Npad / 32;                        // 1564 fused blocks / edge bins

    // workspace layout (~36 MB, no aliasing):
    //   fout16 [Npad*64 uint bf16-pairs] | xf8 [Npad*32 uint] | xb [Npad*64 uint]
    //   | Bsw [32768 bf16] | gsum | gsumsq [G*D f32] | pad[4]
    //   | bcnt [NB32*16 uint, 1 counter/64B line] | bnd[G+1] | bbuf [NB32*BINCAP uint]
    unsigned int*   fout16 = (unsigned int*)d_ws;
    unsigned int*   xf8  = fout16 + (size_t)Npad * 64;
    unsigned int*   xb   = xf8 + (size_t)Npad * 32;
    unsigned short* Bsw  = (unsigned short*)(xb + (size_t)Npad * 64);
    float* gsum   = (float*)(Bsw + 32768);
    float* gsumsq = gsum + NGRAPH * D;
    unsigned int* pad  = (unsigned int*)(gsumsq + NGRAPH * D);
    unsigned int* bcnt = pad + 4;
    int*          bnd  = (int*)(bcnt + (size_t)NB32 * 16);
    unsigned int* bbuf = (unsigned int*)(bnd + (NGRAPH + 1));

    // zero gsum, gsumsq, pad, bcnt (contiguous ~108 KB)
    hipMemsetAsync(gsum, 0,
                   (2 * NGRAPH * D) * sizeof(float) + 4 * sizeof(unsigned int)
                   + (size_t)NB32 * 16 * sizeof(unsigned int), stream);

    int fillB = (E + 1023) / 1024;               // 4 edges/thread
    int xbB   = (Npad * 32 + 255) / 256;
    prep_fill_kernel<<<129 + fillB + xbB, 256, 0, stream>>>(
        Wl, Wr, Bsw, x, xb, xf8, batch, bnd, ei, bcnt, bbuf, N, E, Npad, fillB);

    // fused bin-sort gather + gemm (block = 32 nodes = 1 bin, 8 blk/CU)
    fused_kernel<<<NB32, 256, 0, stream>>>(
        (const unsigned short*)xf8, bcnt, bbuf,
        (const unsigned short*)xb, Bsw, bl, batch,
        gsum, gsumsq, (unsigned short*)fout16, N);

    {
        int threads = N * (D / 4);
        final_kernel<<<(threads + 255) / 256, 256, 0, stream>>>(
            fout16, x, batch, bnd, gsum, gsumsq, ms, gw, gb, out, N);
    }
}